// Round 6
// baseline (177.957 us; speedup 1.0000x reference)
//
#include <hip/hip_runtime.h>

#define D 512
#define NH 8
#define DH 64
#define CCTX 64
#define LN_EPS 1e-5f
#define NCHAIN 128          // blocks participating in the chain barrier
#define NGRID  2048         // total blocks in k_chain (rest prefetch H) and k_final

// workspace float offsets
#define WS_T     0        // 8
#define WS_M     512      // 4096
#define WS_CTX   5120     // 64*512
#define WS_CBAR  40960    // 4096
#define WS_O     45056    // 512
#define WS_OUT1  45568    // 512
#define WS_V     46080    // 512
#define WS_ATTN2 46592    // 512
#define WS_FLAGS 47104    // 128 unsigned (per-block barrier flags)

typedef float f4v __attribute__((ext_vector_type(4)));

__device__ __forceinline__ float waveReduceSum(float v) {
#pragma unroll
    for (int off = 32; off > 0; off >>= 1) v += __shfl_xor(v, off);
    return v;
}

// Contention-free barrier among blocks 0..127: block b release-stores `phase`
// to flags[b]; one wave spins with acquire loads until all 128 flags reach
// `phase`. k_init zeroes flags each launch (graph-replay deterministic).
__device__ __forceinline__ void barFlags(unsigned* flags, unsigned phase) {
    __syncthreads();
    if (threadIdx.x == 0)
        __hip_atomic_store(&flags[blockIdx.x], phase, __ATOMIC_RELEASE,
                           __HIP_MEMORY_SCOPE_AGENT);
    if (threadIdx.x < 64) {
        bool ok;
        do {
            unsigned f0 = __hip_atomic_load(&flags[threadIdx.x], __ATOMIC_ACQUIRE,
                                            __HIP_MEMORY_SCOPE_AGENT);
            unsigned f1 = __hip_atomic_load(&flags[64 + threadIdx.x], __ATOMIC_ACQUIRE,
                                            __HIP_MEMORY_SCOPE_AGENT);
            ok = (f0 >= phase) && (f1 >= phase);
            if (!__all(ok)) __builtin_amdgcn_s_sleep(1); else break;
        } while (true);
    }
    __syncthreads();
}

__global__ __launch_bounds__(128) void k_init(unsigned* flags) {
    flags[threadIdx.x] = 0u;
}

// wave-per-row matvec helper: y[r] = W[r,:] . x(+head offset) + b[r]
__device__ __forceinline__ void matvec_rows(
    const float* __restrict__ W, const float* __restrict__ x,
    const float* __restrict__ b, float* __restrict__ y, int headStride)
{
    int wib = threadIdx.x >> 6, lane = threadIdx.x & 63;
    int r = blockIdx.x * 4 + wib;                    // 0..511
    const float* xr = x + (r >> 6) * headStride;
    const float* Wr = W + (size_t)r * D;
    float4 w0 = *(const float4*)(Wr + lane * 4);
    float4 w1 = *(const float4*)(Wr + 256 + lane * 4);
    float4 x0 = *(const float4*)(xr + lane * 4);
    float4 x1 = *(const float4*)(xr + 256 + lane * 4);
    float s = w0.x*x0.x + w0.y*x0.y + w0.z*x0.z + w0.w*x0.w
            + w1.x*x1.x + w1.y*x1.y + w1.z*x1.z + w1.w*x1.w;
    s = waveReduceSum(s);
    if (lane == 0) y[r] = s + b[r];
}

// Blocks 0..127: the small chain with 5 barriers (identical to round 3).
// Blocks 128..2047: stream-read H with cache-allocating loads -> L3 warm for
// k_final (its NT stores won't evict H). Runs in the chain's BW-idle window.
__global__ __launch_bounds__(256) void k_chain(
    const float* __restrict__ Hm,   const float* __restrict__ path,
    const float* __restrict__ Win1, const float* __restrict__ bin1,
    const float* __restrict__ Wout1,const float* __restrict__ bout1,
    const float* __restrict__ Win2, const float* __restrict__ bin2,
    const float* __restrict__ Wout2,const float* __restrict__ bout2,
    const float* __restrict__ ln1g, const float* __restrict__ ln1b,
    const int* __restrict__ ids,    float* __restrict__ ws, int N)
{
    __shared__ __align__(16) float smem[532];
    unsigned* flags = (unsigned*)(ws + WS_FLAGS);
    const int B = blockIdx.x, tid = threadIdx.x;
    const int wib = tid >> 6, lane = tid & 63;

    if (B >= NCHAIN) {
        // ---- H prefetch: contiguous chunk per block ----
        const int pb = B - NCHAIN;                     // 0..1919
        const int ROWS_PB = 53;                        // ceil(100000/1920)
        const size_t total_f4 = (size_t)N * (D / 4);
        size_t start = (size_t)pb * ROWS_PB * (D / 4);
        size_t end   = start + (size_t)ROWS_PB * (D / 4);
        if (end > total_f4) end = total_f4;
        const float4* Hf4 = (const float4*)Hm;
        for (size_t i = start + tid; i < end; i += 256) {
            float4 v = Hf4[i];
            asm volatile("" :: "v"(v.x), "v"(v.y), "v"(v.z), "v"(v.w));
        }
        return;
    }

    // ---- P0: gather ctx (blocks 0..63) ; qh+m+t per half-head (blocks 64..79) ----
    if (B < 64) {
        if (tid < 128) {
            int id = ids[B];
            float4 v = *(const float4*)(Hm + (size_t)id * D + tid * 4);
            *(float4*)(ws + WS_CTX + B * D + tid * 4) = v;
        }
    } else if (B < 80) {
        int bm = B - 64;                 // 0..15
        int h = bm >> 1, half = bm & 1;
        float* qh_lds = smem;            // 64 floats: qh for head h
        // qh[h*64+r] = Wq[h*64+r,:] . path + bq  — 4 threads per row
        {
            int r = tid >> 2, p = tid & 3;
            const float* wrow = Win1 + (size_t)(h * DH + r) * D + p * 128;
            const float* xrow = path + p * 128;
            float s = 0.f;
#pragma unroll 8
            for (int k = 0; k < 32; ++k) {
                float4 a = *(const float4*)(wrow + k * 4);
                float4 c = *(const float4*)(xrow + k * 4);
                s += a.x*c.x + a.y*c.y + a.z*c.z + a.w*c.w;
            }
            s += __shfl_xor(s, 1);
            s += __shfl_xor(s, 2);
            if (p == 0) qh_lds[r] = s + bin1[h * DH + r];
        }
        __syncthreads();
        // m[h][c] = sum_d Wk[h*64+d][c] * qh[d]
        {
            int c = half * 256 + tid;
            const float* Wk = Win1 + (size_t)D * D;
            float acc = 0.f;
#pragma unroll 8
            for (int d = 0; d < DH; ++d)
                acc += Wk[(size_t)(h * DH + d) * D + c] * qh_lds[d];
            ws[WS_M + h * D + c] = acc;
        }
        if (half == 0 && tid == 0) {
            float tt = 0.f;
            for (int d = 0; d < DH; ++d) tt += bin1[D + h * DH + d] * qh_lds[d];
            ws[WS_T + h] = tt;
        }
    }
    barFlags(flags, 1);

    // ---- P1: blocks 0..7 (one per head) — scores -> softmax -> cbar_h ----
    if (B < NH) {
        const int h = B;
        float* s_lds = smem;          // 64 scores
        float* w_lds = smem + 64;     // 64 weights
        // scores[j] = ctx_j . m_h + t_h  — 4 threads per j
        {
            int j = tid >> 2, p = tid & 3;
            const float* cr = ws + WS_CTX + j * D + p * 128;
            const float* mr = ws + WS_M + h * D + p * 128;
            float s = 0.f;
#pragma unroll 8
            for (int c4 = 0; c4 < 32; ++c4) {
                float4 a = *(const float4*)(cr + c4 * 4);
                float4 b = *(const float4*)(mr + c4 * 4);
                s += a.x*b.x + a.y*b.y + a.z*b.z + a.w*b.w;
            }
            s += __shfl_xor(s, 1);
            s += __shfl_xor(s, 2);
            if (p == 0) s_lds[j] = (s + ws[WS_T + h]) * 0.125f;
        }
        __syncthreads();
        // softmax over 64 scores — wave 0
        if (wib == 0) {
            float sc = s_lds[lane];
            float mx = sc;
#pragma unroll
            for (int off = 32; off > 0; off >>= 1) mx = fmaxf(mx, __shfl_xor(mx, off));
            float e = __expf(sc - mx);
            float sum = waveReduceSum(e);
            w_lds[lane] = e / sum;
        }
        __syncthreads();
        // cbar[h][c] — thread owns columns tid, tid+256
        for (int c = tid; c < D; c += 256) {
            float acc = 0.f;
#pragma unroll 8
            for (int j = 0; j < CCTX; ++j) acc += w_lds[j] * ws[WS_CTX + j * D + c];
            ws[WS_CBAR + h * D + c] = acc;
        }
    }
    barFlags(flags, 2);

    // ---- P2: o = Wv @ cbar + bv (per-head x) ----
    matvec_rows(Win1 + 2 * (size_t)D * D, ws + WS_CBAR, bin1 + 2 * D, ws + WS_O, D);
    barFlags(flags, 3);

    // ---- P3: out1 = Wout1 @ o + bout1 ----
    matvec_rows(Wout1, ws + WS_O, bout1, ws + WS_OUT1, 0);
    barFlags(flags, 4);

    // ---- P4: xs = LN(out1 + path)*g1+b1 (per block), v = Wv2 @ xs + bv2 ----
    {
        float* xs  = smem;          // 512
        float* red = smem + 520;    // 8
        float a0 = ws[WS_OUT1 + tid * 2]     + path[tid * 2];
        float a1 = ws[WS_OUT1 + tid * 2 + 1] + path[tid * 2 + 1];
        float s  = a0 + a1;
        float s2 = a0 * a0 + a1 * a1;
        s  = waveReduceSum(s);
        s2 = waveReduceSum(s2);
        if (lane == 0) { red[wib] = s; red[4 + wib] = s2; }
        __syncthreads();
        float st  = red[0] + red[1] + red[2] + red[3];
        float s2t = red[4] + red[5] + red[6] + red[7];
        float mu   = st * (1.f / D);
        float var  = s2t * (1.f / D) - mu * mu;
        float rinv = rsqrtf(var + LN_EPS);
        xs[tid * 2]     = (a0 - mu) * rinv * ln1g[tid * 2]     + ln1b[tid * 2];
        xs[tid * 2 + 1] = (a1 - mu) * rinv * ln1g[tid * 2 + 1] + ln1b[tid * 2 + 1];
        __syncthreads();
        matvec_rows(Win2 + 2 * (size_t)D * D, xs, bin2 + 2 * D, ws + WS_V, 0);
    }
    barFlags(flags, 5);

    // ---- P5: attn2 = Wout2 @ v + bout2 ----
    matvec_rows(Wout2, ws + WS_V, bout2, ws + WS_ATTN2, 0);
}

// H_cond[i,:] = LN(attn2 + H[i,:]) * g + b — wave per row, contiguous block
// ranges (DRAM/L3 locality), NT stores (don't evict L3-resident H).
__global__ __launch_bounds__(256) void k_final(
    const float* __restrict__ Hm, const float* __restrict__ attn2,
    const float* __restrict__ g, const float* __restrict__ b,
    float* __restrict__ out, int N)
{
    int lane = threadIdx.x & 63;
    int wib  = threadIdx.x >> 6;
    int c0 = lane * 4, c1 = 256 + lane * 4;
    float4 a0 = *(const float4*)(attn2 + c0), a1 = *(const float4*)(attn2 + c1);
    float4 g0 = *(const float4*)(g + c0),     g1 = *(const float4*)(g + c1);
    float4 b0 = *(const float4*)(b + c0),     b1 = *(const float4*)(b + c1);
    const int CHF = 49;                          // ceil(100000/2048)
    int s0r = blockIdx.x * CHF;
    int e0r = s0r + CHF; if (e0r > N) e0r = N;
    for (int row = s0r + wib; row < e0r; row += 4) {
        const float* hr = Hm + (size_t)row * D;
        float4 x0 = *(const float4*)(hr + c0);
        float4 x1 = *(const float4*)(hr + c1);
        x0.x += a0.x; x0.y += a0.y; x0.z += a0.z; x0.w += a0.w;
        x1.x += a1.x; x1.y += a1.y; x1.z += a1.z; x1.w += a1.w;
        float s  = x0.x + x0.y + x0.z + x0.w + x1.x + x1.y + x1.z + x1.w;
        float s2 = x0.x*x0.x + x0.y*x0.y + x0.z*x0.z + x0.w*x0.w
                 + x1.x*x1.x + x1.y*x1.y + x1.z*x1.z + x1.w*x1.w;
#pragma unroll
        for (int off = 32; off > 0; off >>= 1) {
            s  += __shfl_xor(s, off);
            s2 += __shfl_xor(s2, off);
        }
        float mu   = s * (1.f / D);
        float var  = s2 * (1.f / D) - mu * mu;
        float rinv = rsqrtf(var + LN_EPS);
        f4v y0, y1;
        y0.x = (x0.x - mu) * rinv * g0.x + b0.x;
        y0.y = (x0.y - mu) * rinv * g0.y + b0.y;
        y0.z = (x0.z - mu) * rinv * g0.z + b0.z;
        y0.w = (x0.w - mu) * rinv * g0.w + b0.w;
        y1.x = (x1.x - mu) * rinv * g1.x + b1.x;
        y1.y = (x1.y - mu) * rinv * g1.y + b1.y;
        y1.z = (x1.z - mu) * rinv * g1.z + b1.z;
        y1.w = (x1.w - mu) * rinv * g1.w + b1.w;
        float* orow = out + (size_t)row * D;
        __builtin_nontemporal_store(y0, (f4v*)(orow + c0));
        __builtin_nontemporal_store(y1, (f4v*)(orow + c1));
    }
}

extern "C" void kernel_launch(void* const* d_in, const int* in_sizes, int n_in,
                              void* d_out, int out_size, void* d_ws, size_t ws_size,
                              hipStream_t stream)
{
    const float* Hm    = (const float*)d_in[0];
    const float* path  = (const float*)d_in[1];
    const float* Win1  = (const float*)d_in[2];
    const float* bin1  = (const float*)d_in[3];
    const float* Wout1 = (const float*)d_in[4];
    const float* bout1 = (const float*)d_in[5];
    const float* Win2  = (const float*)d_in[6];
    const float* bin2  = (const float*)d_in[7];
    const float* Wout2 = (const float*)d_in[8];
    const float* bout2 = (const float*)d_in[9];
    const float* ln1g  = (const float*)d_in[10];
    const float* ln1b  = (const float*)d_in[11];
    const float* ln2g  = (const float*)d_in[12];
    const float* ln2b  = (const float*)d_in[13];
    // d_in[14] = edge_index — unused by the reference
    const int*   ids   = (const int*)d_in[15];

    float* ws  = (float*)d_ws;
    float* out = (float*)d_out;
    const int N = in_sizes[0] / D;

    k_init<<<1, 128, 0, stream>>>((unsigned*)(ws + WS_FLAGS));
    k_chain<<<NGRID, 256, 0, stream>>>(Hm, path, Win1, bin1, Wout1, bout1,
                                       Win2, bin2, Wout2, bout2, ln1g, ln1b,
                                       ids, ws, N);
    k_final<<<NGRID, 256, 0, stream>>>(Hm, ws + WS_ATTN2, ln2g, ln2b, out, N);
}

// Round 7
// 173.819 us; speedup vs baseline: 1.0238x; 1.0238x over previous
//
#include <hip/hip_runtime.h>

#define D 512
#define NH 8
#define DH 64
#define CCTX 64
#define LN_EPS 1e-5f
#define NCHAIN 128          // blocks participating in the chain barrier
#define NGRID  2048         // total blocks
#define CHF    49           // final rows per block: ceil(100000/2048)

// workspace float offsets
#define WS_T     0        // 8
#define WS_M     512      // 4096
#define WS_CTX   5120     // 64*512
#define WS_CBAR  40960    // 4096
#define WS_O     45056    // 512
#define WS_OUT1  45568    // 512
#define WS_V     46080    // 512
#define WS_ATTN2 46592    // 512
#define WS_FLAGS 47104    // 128 unsigned (per-block barrier flags)

typedef float f4v __attribute__((ext_vector_type(4)));

__device__ __forceinline__ float waveReduceSum(float v) {
#pragma unroll
    for (int off = 32; off > 0; off >>= 1) v += __shfl_xor(v, off);
    return v;
}

// Wait until all 128 chain flags reach `phase`. RELAXED polls (no cache
// invalidation per iteration!) + ONE acquire fence on exit. The per-poll
// ACQUIRE load variant emitted buffer_inv each iteration and collapsed
// chip bandwidth to 690 GB/s in round 6.
__device__ __forceinline__ void spinAll(unsigned* flags, unsigned phase) {
    if (threadIdx.x < 64) {
        while (true) {
            unsigned f0 = __hip_atomic_load(&flags[threadIdx.x],
                                            __ATOMIC_RELAXED, __HIP_MEMORY_SCOPE_AGENT);
            unsigned f1 = __hip_atomic_load(&flags[64 + threadIdx.x],
                                            __ATOMIC_RELAXED, __HIP_MEMORY_SCOPE_AGENT);
            if (__all(f0 >= phase && f1 >= phase)) break;
            __builtin_amdgcn_s_sleep(8);
        }
        __builtin_amdgcn_fence(__ATOMIC_ACQUIRE, "agent");
    }
    __syncthreads();
}

// Chain-block barrier: release own flag, then wait for all.
__device__ __forceinline__ void barFlags(unsigned* flags, unsigned phase) {
    __syncthreads();
    if (threadIdx.x == 0)
        __hip_atomic_store(&flags[blockIdx.x], phase, __ATOMIC_RELEASE,
                           __HIP_MEMORY_SCOPE_AGENT);
    spinAll(flags, phase);
}

__global__ __launch_bounds__(128) void k_init(unsigned* flags) {
    flags[threadIdx.x] = 0u;
}

// wave-per-row matvec helper: y[r] = W[r,:] . x(+head offset) + b[r]
__device__ __forceinline__ void matvec_rows(
    const float* __restrict__ W, const float* __restrict__ x,
    const float* __restrict__ b, float* __restrict__ y, int headStride)
{
    int wib = threadIdx.x >> 6, lane = threadIdx.x & 63;
    int r = blockIdx.x * 4 + wib;                    // 0..511
    const float* xr = x + (r >> 6) * headStride;
    const float* Wr = W + (size_t)r * D;
    float4 w0 = *(const float4*)(Wr + lane * 4);
    float4 w1 = *(const float4*)(Wr + 256 + lane * 4);
    float4 x0 = *(const float4*)(xr + lane * 4);
    float4 x1 = *(const float4*)(xr + 256 + lane * 4);
    float s = w0.x*x0.x + w0.y*x0.y + w0.z*x0.z + w0.w*x0.w
            + w1.x*x1.x + w1.y*x1.y + w1.z*x1.z + w1.w*x1.w;
    s = waveReduceSum(s);
    if (lane == 0) y[r] = s + b[r];
}

// ONE kernel: blocks 0..127 run the small chain (5 barriers); blocks
// 128..2047 prefetch their own final row-chunk of H into L3, then wait for
// flag 6; finally ALL blocks run the big LN with NT stores.
__global__ __launch_bounds__(256) void k_fused(
    const float* __restrict__ Hm,   const float* __restrict__ path,
    const float* __restrict__ Win1, const float* __restrict__ bin1,
    const float* __restrict__ Wout1,const float* __restrict__ bout1,
    const float* __restrict__ Win2, const float* __restrict__ bin2,
    const float* __restrict__ Wout2,const float* __restrict__ bout2,
    const float* __restrict__ ln1g, const float* __restrict__ ln1b,
    const float* __restrict__ ln2g, const float* __restrict__ ln2b,
    const int* __restrict__ ids,    float* __restrict__ ws,
    float* __restrict__ out, int N)
{
    __shared__ __align__(16) float smem[532];
    unsigned* flags = (unsigned*)(ws + WS_FLAGS);
    const int B = blockIdx.x, tid = threadIdx.x;
    const int wib = tid >> 6, lane = tid & 63;

    if (B >= NCHAIN) {
        // ---- prefetch this block's own final chunk into L3 (pipelined loads) ----
        int s0r = B * CHF;
        int e0r = s0r + CHF; if (e0r > N) e0r = N;
        const float4* Hf4 = (const float4*)Hm;
        float acc = 0.f;
        for (int i = s0r * (D / 4) + tid; i < e0r * (D / 4); i += 256) {
            float4 v = Hf4[i];
            acc += v.x + v.y + v.z + v.w;
        }
        asm volatile("" :: "v"(acc));
        spinAll(flags, 6);
    } else {
        // ---- P0: gather ctx (blocks 0..63); qh+m+t per half-head (64..79) ----
        if (B < 64) {
            if (tid < 128) {
                int id = ids[B];
                float4 v = *(const float4*)(Hm + (size_t)id * D + tid * 4);
                *(float4*)(ws + WS_CTX + B * D + tid * 4) = v;
            }
        } else if (B < 80) {
            int bm = B - 64;                 // 0..15
            int h = bm >> 1, half = bm & 1;
            float* qh_lds = smem;            // 64 floats: qh for head h
            // qh[h*64+r] = Wq[h*64+r,:] . path + bq  — 4 threads per row
            {
                int r = tid >> 2, p = tid & 3;
                const float* wrow = Win1 + (size_t)(h * DH + r) * D + p * 128;
                const float* xrow = path + p * 128;
                float s = 0.f;
#pragma unroll 8
                for (int k = 0; k < 32; ++k) {
                    float4 a = *(const float4*)(wrow + k * 4);
                    float4 c = *(const float4*)(xrow + k * 4);
                    s += a.x*c.x + a.y*c.y + a.z*c.z + a.w*c.w;
                }
                s += __shfl_xor(s, 1);
                s += __shfl_xor(s, 2);
                if (p == 0) qh_lds[r] = s + bin1[h * DH + r];
            }
            __syncthreads();
            // m[h][c] = sum_d Wk[h*64+d][c] * qh[d]
            {
                int c = half * 256 + tid;
                const float* Wk = Win1 + (size_t)D * D;
                float acc = 0.f;
#pragma unroll 8
                for (int d = 0; d < DH; ++d)
                    acc += Wk[(size_t)(h * DH + d) * D + c] * qh_lds[d];
                ws[WS_M + h * D + c] = acc;
            }
            if (half == 0 && tid == 0) {
                float tt = 0.f;
                for (int d = 0; d < DH; ++d) tt += bin1[D + h * DH + d] * qh_lds[d];
                ws[WS_T + h] = tt;
            }
        }
        barFlags(flags, 1);

        // ---- P1: blocks 0..7 (one per head) — scores -> softmax -> cbar_h ----
        if (B < NH) {
            const int h = B;
            float* s_lds = smem;          // 64 scores
            float* w_lds = smem + 64;     // 64 weights
            {
                int j = tid >> 2, p = tid & 3;
                const float* cr = ws + WS_CTX + j * D + p * 128;
                const float* mr = ws + WS_M + h * D + p * 128;
                float s = 0.f;
#pragma unroll 8
                for (int c4 = 0; c4 < 32; ++c4) {
                    float4 a = *(const float4*)(cr + c4 * 4);
                    float4 b = *(const float4*)(mr + c4 * 4);
                    s += a.x*b.x + a.y*b.y + a.z*b.z + a.w*b.w;
                }
                s += __shfl_xor(s, 1);
                s += __shfl_xor(s, 2);
                if (p == 0) s_lds[j] = (s + ws[WS_T + h]) * 0.125f;
            }
            __syncthreads();
            if (wib == 0) {
                float sc = s_lds[lane];
                float mx = sc;
#pragma unroll
                for (int off = 32; off > 0; off >>= 1) mx = fmaxf(mx, __shfl_xor(mx, off));
                float e = __expf(sc - mx);
                float sum = waveReduceSum(e);
                w_lds[lane] = e / sum;
            }
            __syncthreads();
            for (int c = tid; c < D; c += 256) {
                float acc = 0.f;
#pragma unroll 8
                for (int j = 0; j < CCTX; ++j) acc += w_lds[j] * ws[WS_CTX + j * D + c];
                ws[WS_CBAR + h * D + c] = acc;
            }
        }
        barFlags(flags, 2);

        // ---- P2: o = Wv @ cbar + bv (per-head x) ----
        matvec_rows(Win1 + 2 * (size_t)D * D, ws + WS_CBAR, bin1 + 2 * D, ws + WS_O, D);
        barFlags(flags, 3);

        // ---- P3: out1 = Wout1 @ o + bout1 ----
        matvec_rows(Wout1, ws + WS_O, bout1, ws + WS_OUT1, 0);
        barFlags(flags, 4);

        // ---- P4: xs = LN(out1 + path)*g1+b1, v = Wv2 @ xs + bv2 ----
        {
            float* xs  = smem;          // 512
            float* red = smem + 520;    // 8
            float a0 = ws[WS_OUT1 + tid * 2]     + path[tid * 2];
            float a1 = ws[WS_OUT1 + tid * 2 + 1] + path[tid * 2 + 1];
            float s  = a0 + a1;
            float s2 = a0 * a0 + a1 * a1;
            s  = waveReduceSum(s);
            s2 = waveReduceSum(s2);
            if (lane == 0) { red[wib] = s; red[4 + wib] = s2; }
            __syncthreads();
            float st  = red[0] + red[1] + red[2] + red[3];
            float s2t = red[4] + red[5] + red[6] + red[7];
            float mu   = st * (1.f / D);
            float var  = s2t * (1.f / D) - mu * mu;
            float rinv = rsqrtf(var + LN_EPS);
            xs[tid * 2]     = (a0 - mu) * rinv * ln1g[tid * 2]     + ln1b[tid * 2];
            xs[tid * 2 + 1] = (a1 - mu) * rinv * ln1g[tid * 2 + 1] + ln1b[tid * 2 + 1];
            __syncthreads();
            matvec_rows(Win2 + 2 * (size_t)D * D, xs, bin2 + 2 * D, ws + WS_V, 0);
        }
        barFlags(flags, 5);

        // ---- P5: attn2 = Wout2 @ v + bout2, then release flag 6 + wait ----
        matvec_rows(Wout2, ws + WS_V, bout2, ws + WS_ATTN2, 0);
        barFlags(flags, 6);
    }

    // ---- FINAL (all 2048 blocks): H_cond[i,:] = LN(attn2 + H[i,:])*g2+b2 ----
    {
        const float* attn2 = ws + WS_ATTN2;
        int c0 = lane * 4, c1 = 256 + lane * 4;
        float4 a0 = *(const float4*)(attn2 + c0), a1 = *(const float4*)(attn2 + c1);
        float4 g0 = *(const float4*)(ln2g + c0),  g1 = *(const float4*)(ln2g + c1);
        float4 b0 = *(const float4*)(ln2b + c0),  b1 = *(const float4*)(ln2b + c1);
        int s0r = B * CHF;
        int e0r = s0r + CHF; if (e0r > N) e0r = N;
        for (int row = s0r + wib; row < e0r; row += 4) {
            const float* hr = Hm + (size_t)row * D;
            float4 x0 = *(const float4*)(hr + c0);
            float4 x1 = *(const float4*)(hr + c1);
            x0.x += a0.x; x0.y += a0.y; x0.z += a0.z; x0.w += a0.w;
            x1.x += a1.x; x1.y += a1.y; x1.z += a1.z; x1.w += a1.w;
            float s  = x0.x + x0.y + x0.z + x0.w + x1.x + x1.y + x1.z + x1.w;
            float s2 = x0.x*x0.x + x0.y*x0.y + x0.z*x0.z + x0.w*x0.w
                     + x1.x*x1.x + x1.y*x1.y + x1.z*x1.z + x1.w*x1.w;
#pragma unroll
            for (int off = 32; off > 0; off >>= 1) {
                s  += __shfl_xor(s, off);
                s2 += __shfl_xor(s2, off);
            }
            float mu   = s * (1.f / D);
            float var  = s2 * (1.f / D) - mu * mu;
            float rinv = rsqrtf(var + LN_EPS);
            f4v y0, y1;
            y0.x = (x0.x - mu) * rinv * g0.x + b0.x;
            y0.y = (x0.y - mu) * rinv * g0.y + b0.y;
            y0.z = (x0.z - mu) * rinv * g0.z + b0.z;
            y0.w = (x0.w - mu) * rinv * g0.w + b0.w;
            y1.x = (x1.x - mu) * rinv * g1.x + b1.x;
            y1.y = (x1.y - mu) * rinv * g1.y + b1.y;
            y1.z = (x1.z - mu) * rinv * g1.z + b1.z;
            y1.w = (x1.w - mu) * rinv * g1.w + b1.w;
            float* orow = out + (size_t)row * D;
            __builtin_nontemporal_store(y0, (f4v*)(orow + c0));
            __builtin_nontemporal_store(y1, (f4v*)(orow + c1));
        }
    }
}

extern "C" void kernel_launch(void* const* d_in, const int* in_sizes, int n_in,
                              void* d_out, int out_size, void* d_ws, size_t ws_size,
                              hipStream_t stream)
{
    const float* Hm    = (const float*)d_in[0];
    const float* path  = (const float*)d_in[1];
    const float* Win1  = (const float*)d_in[2];
    const float* bin1  = (const float*)d_in[3];
    const float* Wout1 = (const float*)d_in[4];
    const float* bout1 = (const float*)d_in[5];
    const float* Win2  = (const float*)d_in[6];
    const float* bin2  = (const float*)d_in[7];
    const float* Wout2 = (const float*)d_in[8];
    const float* bout2 = (const float*)d_in[9];
    const float* ln1g  = (const float*)d_in[10];
    const float* ln1b  = (const float*)d_in[11];
    const float* ln2g  = (const float*)d_in[12];
    const float* ln2b  = (const float*)d_in[13];
    // d_in[14] = edge_index — unused by the reference
    const int*   ids   = (const int*)d_in[15];

    float* ws  = (float*)d_ws;
    float* out = (float*)d_out;
    const int N = in_sizes[0] / D;

    k_init<<<1, 128, 0, stream>>>((unsigned*)(ws + WS_FLAGS));
    k_fused<<<NGRID, 256, 0, stream>>>(Hm, path, Win1, bin1, Wout1, bout1,
                                       Win2, bin2, Wout2, bout2, ln1g, ln1b,
                                       ln2g, ln2b, ids, ws, out, N);
}

// Round 8
// 140.845 us; speedup vs baseline: 1.2635x; 1.2341x over previous
//
#include <hip/hip_runtime.h>

#define D 512
#define NH 8
#define DH 64
#define CCTX 64
#define LN_EPS 1e-5f
#define NCHAIN 128

// workspace float offsets
#define WS_T     0        // 8
#define WS_M     512      // 4096
#define WS_CTX   5120     // 64*512
#define WS_CBAR  40960    // 4096
#define WS_O     45056    // 512
#define WS_OUT1  45568    // 512
#define WS_V     46080    // 512
#define WS_ATTN2 46592    // 512
#define WS_FLAGS 47104    // 128 unsigned (per-block barrier flags)

__device__ __forceinline__ float waveReduceSum(float v) {
#pragma unroll
    for (int off = 32; off > 0; off >>= 1) v += __shfl_xor(v, off);
    return v;
}

// Contention-free barrier among the 128 chain blocks. RELAXED polls (no
// per-iteration cache invalidation) + one acquire fence on exit (r7-validated).
__device__ __forceinline__ void barFlags(unsigned* flags, unsigned phase) {
    __syncthreads();
    if (threadIdx.x == 0)
        __hip_atomic_store(&flags[blockIdx.x], phase, __ATOMIC_RELEASE,
                           __HIP_MEMORY_SCOPE_AGENT);
    if (threadIdx.x < 64) {
        while (true) {
            unsigned f0 = __hip_atomic_load(&flags[threadIdx.x],
                                            __ATOMIC_RELAXED, __HIP_MEMORY_SCOPE_AGENT);
            unsigned f1 = __hip_atomic_load(&flags[64 + threadIdx.x],
                                            __ATOMIC_RELAXED, __HIP_MEMORY_SCOPE_AGENT);
            if (__all(f0 >= phase && f1 >= phase)) break;
            __builtin_amdgcn_s_sleep(2);
        }
        __builtin_amdgcn_fence(__ATOMIC_ACQUIRE, "agent");
    }
    __syncthreads();
}

__global__ __launch_bounds__(128) void k_init(unsigned* flags) {
    flags[threadIdx.x] = 0u;
}

// wave-per-row matvec helper: y[r] = W[r,:] . x(+head offset) + b[r]
__device__ __forceinline__ void matvec_rows(
    const float* __restrict__ W, const float* __restrict__ x,
    const float* __restrict__ b, float* __restrict__ y, int headStride)
{
    int wib = threadIdx.x >> 6, lane = threadIdx.x & 63;
    int r = blockIdx.x * 4 + wib;                    // 0..511
    const float* xr = x + (r >> 6) * headStride;
    const float* Wr = W + (size_t)r * D;
    float4 w0 = *(const float4*)(Wr + lane * 4);
    float4 w1 = *(const float4*)(Wr + 256 + lane * 4);
    float4 x0 = *(const float4*)(xr + lane * 4);
    float4 x1 = *(const float4*)(xr + 256 + lane * 4);
    float s = w0.x*x0.x + w0.y*x0.y + w0.z*x0.z + w0.w*x0.w
            + w1.x*x1.x + w1.y*x1.y + w1.z*x1.z + w1.w*x1.w;
    s = waveReduceSum(s);
    if (lane == 0) y[r] = s + b[r];
}

// The small chain: 128 blocks x 256 threads, 5 barriers (round-3 structure).
__global__ __launch_bounds__(256) void k_chain(
    const float* __restrict__ Hm,   const float* __restrict__ path,
    const float* __restrict__ Win1, const float* __restrict__ bin1,
    const float* __restrict__ Wout1,const float* __restrict__ bout1,
    const float* __restrict__ Win2, const float* __restrict__ bin2,
    const float* __restrict__ Wout2,const float* __restrict__ bout2,
    const float* __restrict__ ln1g, const float* __restrict__ ln1b,
    const int* __restrict__ ids,    float* __restrict__ ws)
{
    __shared__ __align__(16) float smem[532];
    unsigned* flags = (unsigned*)(ws + WS_FLAGS);
    const int B = blockIdx.x, tid = threadIdx.x;
    const int wib = tid >> 6, lane = tid & 63;

    // ---- P0: gather ctx (blocks 0..63) ; qh+m+t per half-head (blocks 64..79) ----
    if (B < 64) {
        if (tid < 128) {
            int id = ids[B];
            float4 v = *(const float4*)(Hm + (size_t)id * D + tid * 4);
            *(float4*)(ws + WS_CTX + B * D + tid * 4) = v;
        }
    } else if (B < 80) {
        int bm = B - 64;                 // 0..15
        int h = bm >> 1, half = bm & 1;
        float* qh_lds = smem;            // 64 floats: qh for head h
        {
            int r = tid >> 2, p = tid & 3;
            const float* wrow = Win1 + (size_t)(h * DH + r) * D + p * 128;
            const float* xrow = path + p * 128;
            float s = 0.f;
#pragma unroll 8
            for (int k = 0; k < 32; ++k) {
                float4 a = *(const float4*)(wrow + k * 4);
                float4 c = *(const float4*)(xrow + k * 4);
                s += a.x*c.x + a.y*c.y + a.z*c.z + a.w*c.w;
            }
            s += __shfl_xor(s, 1);
            s += __shfl_xor(s, 2);
            if (p == 0) qh_lds[r] = s + bin1[h * DH + r];
        }
        __syncthreads();
        {
            int c = half * 256 + tid;
            const float* Wk = Win1 + (size_t)D * D;
            float acc = 0.f;
#pragma unroll 8
            for (int d = 0; d < DH; ++d)
                acc += Wk[(size_t)(h * DH + d) * D + c] * qh_lds[d];
            ws[WS_M + h * D + c] = acc;
        }
        if (half == 0 && tid == 0) {
            float tt = 0.f;
            for (int d = 0; d < DH; ++d) tt += bin1[D + h * DH + d] * qh_lds[d];
            ws[WS_T + h] = tt;
        }
    }
    barFlags(flags, 1);

    // ---- P1: blocks 0..7 (one per head) — scores -> softmax -> cbar_h ----
    if (B < NH) {
        const int h = B;
        float* s_lds = smem;          // 64 scores
        float* w_lds = smem + 64;     // 64 weights
        {
            int j = tid >> 2, p = tid & 3;
            const float* cr = ws + WS_CTX + j * D + p * 128;
            const float* mr = ws + WS_M + h * D + p * 128;
            float s = 0.f;
#pragma unroll 8
            for (int c4 = 0; c4 < 32; ++c4) {
                float4 a = *(const float4*)(cr + c4 * 4);
                float4 b = *(const float4*)(mr + c4 * 4);
                s += a.x*b.x + a.y*b.y + a.z*b.z + a.w*b.w;
            }
            s += __shfl_xor(s, 1);
            s += __shfl_xor(s, 2);
            if (p == 0) s_lds[j] = (s + ws[WS_T + h]) * 0.125f;
        }
        __syncthreads();
        if (wib == 0) {
            float sc = s_lds[lane];
            float mx = sc;
#pragma unroll
            for (int off = 32; off > 0; off >>= 1) mx = fmaxf(mx, __shfl_xor(mx, off));
            float e = __expf(sc - mx);
            float sum = waveReduceSum(e);
            w_lds[lane] = e / sum;
        }
        __syncthreads();
        for (int c = tid; c < D; c += 256) {
            float acc = 0.f;
#pragma unroll 8
            for (int j = 0; j < CCTX; ++j) acc += w_lds[j] * ws[WS_CTX + j * D + c];
            ws[WS_CBAR + h * D + c] = acc;
        }
    }
    barFlags(flags, 2);

    // ---- P2: o = Wv @ cbar + bv (per-head x) ----
    matvec_rows(Win1 + 2 * (size_t)D * D, ws + WS_CBAR, bin1 + 2 * D, ws + WS_O, D);
    barFlags(flags, 3);

    // ---- P3: out1 = Wout1 @ o + bout1 ----
    matvec_rows(Wout1, ws + WS_O, bout1, ws + WS_OUT1, 0);
    barFlags(flags, 4);

    // ---- P4: xs = LN(out1 + path)*g1+b1, v = Wv2 @ xs + bv2 ----
    {
        float* xs  = smem;          // 512
        float* red = smem + 520;    // 8
        float a0 = ws[WS_OUT1 + tid * 2]     + path[tid * 2];
        float a1 = ws[WS_OUT1 + tid * 2 + 1] + path[tid * 2 + 1];
        float s  = a0 + a1;
        float s2 = a0 * a0 + a1 * a1;
        s  = waveReduceSum(s);
        s2 = waveReduceSum(s2);
        if (lane == 0) { red[wib] = s; red[4 + wib] = s2; }
        __syncthreads();
        float st  = red[0] + red[1] + red[2] + red[3];
        float s2t = red[4] + red[5] + red[6] + red[7];
        float mu   = st * (1.f / D);
        float var  = s2t * (1.f / D) - mu * mu;
        float rinv = rsqrtf(var + LN_EPS);
        xs[tid * 2]     = (a0 - mu) * rinv * ln1g[tid * 2]     + ln1b[tid * 2];
        xs[tid * 2 + 1] = (a1 - mu) * rinv * ln1g[tid * 2 + 1] + ln1b[tid * 2 + 1];
        __syncthreads();
        matvec_rows(Win2 + 2 * (size_t)D * D, xs, bin2 + 2 * D, ws + WS_V, 0);
    }
    barFlags(flags, 5);

    // ---- P5: attn2 = Wout2 @ v + bout2 ----
    matvec_rows(Wout2, ws + WS_V, bout2, ws + WS_ATTN2, 0);
}

// H_cond[i,:] = LN(attn2 + H[i,:]) * g + b
// MLP-optimized: 2 rows per wave per iteration (independent reduce chains)
// + software prefetch of next iteration's 4x float4 -> ~8 loads in flight.
__global__ __launch_bounds__(256) void k_final(
    const float* __restrict__ Hm, const float* __restrict__ attn2,
    const float* __restrict__ g, const float* __restrict__ b,
    float* __restrict__ out, int N)
{
    const int lane = threadIdx.x & 63;
    const int wib  = threadIdx.x >> 6;
    const int w    = blockIdx.x * 4 + wib;          // 0..8191
    const int STRIDE = 16384;                        // 8192 waves * 2 rows

    const int c0 = lane * 4, c1 = 256 + lane * 4;
    float4 a0 = *(const float4*)(attn2 + c0), a1 = *(const float4*)(attn2 + c1);
    float4 g0 = *(const float4*)(g + c0),     g1 = *(const float4*)(g + c1);
    float4 b0 = *(const float4*)(b + c0),     b1 = *(const float4*)(b + c1);

    const float4* H4 = (const float4*)Hm;
    float4*       O4 = (float4*)out;
    const float4  z4 = {0.f, 0.f, 0.f, 0.f};

    int base = w * 2;
    if (base >= N) return;

    size_t i0 = (size_t)base * 128 + lane;
    float4 xa0 = H4[i0], xa1 = H4[i0 + 64];
    bool hasB = (base + 1) < N;
    float4 xb0 = hasB ? H4[i0 + 128] : z4;
    float4 xb1 = hasB ? H4[i0 + 192] : z4;

    while (true) {
        int  nbase = base + STRIDE;
        bool more  = nbase < N;
        float4 na0, na1, nb0, nb1;
        bool nHasB = false;
        if (more) {
            size_t ii = (size_t)nbase * 128 + lane;
            na0 = H4[ii]; na1 = H4[ii + 64];
            nHasB = (nbase + 1) < N;
            nb0 = nHasB ? H4[ii + 128] : z4;
            nb1 = nHasB ? H4[ii + 192] : z4;
        }

        // add attn2
        float4 pa0, pa1, pb0, pb1;
        pa0.x = xa0.x + a0.x; pa0.y = xa0.y + a0.y; pa0.z = xa0.z + a0.z; pa0.w = xa0.w + a0.w;
        pa1.x = xa1.x + a1.x; pa1.y = xa1.y + a1.y; pa1.z = xa1.z + a1.z; pa1.w = xa1.w + a1.w;
        pb0.x = xb0.x + a0.x; pb0.y = xb0.y + a0.y; pb0.z = xb0.z + a0.z; pb0.w = xb0.w + a0.w;
        pb1.x = xb1.x + a1.x; pb1.y = xb1.y + a1.y; pb1.z = xb1.z + a1.z; pb1.w = xb1.w + a1.w;

        float sA  = pa0.x + pa0.y + pa0.z + pa0.w + pa1.x + pa1.y + pa1.z + pa1.w;
        float s2A = pa0.x*pa0.x + pa0.y*pa0.y + pa0.z*pa0.z + pa0.w*pa0.w
                  + pa1.x*pa1.x + pa1.y*pa1.y + pa1.z*pa1.z + pa1.w*pa1.w;
        float sB  = pb0.x + pb0.y + pb0.z + pb0.w + pb1.x + pb1.y + pb1.z + pb1.w;
        float s2B = pb0.x*pb0.x + pb0.y*pb0.y + pb0.z*pb0.z + pb0.w*pb0.w
                  + pb1.x*pb1.x + pb1.y*pb1.y + pb1.z*pb1.z + pb1.w*pb1.w;

        // two independent reduce chains, interleaved (ILP=2, x2 for s/s2)
#pragma unroll
        for (int off = 32; off > 0; off >>= 1) {
            sA  += __shfl_xor(sA,  off);
            s2A += __shfl_xor(s2A, off);
            sB  += __shfl_xor(sB,  off);
            s2B += __shfl_xor(s2B, off);
        }

        float muA   = sA * (1.f / D);
        float varA  = s2A * (1.f / D) - muA * muA;
        float rinvA = rsqrtf(varA + LN_EPS);
        float muB   = sB * (1.f / D);
        float varB  = s2B * (1.f / D) - muB * muB;
        float rinvB = rsqrtf(varB + LN_EPS);

        float4 y;
        y.x = (pa0.x - muA) * rinvA * g0.x + b0.x;
        y.y = (pa0.y - muA) * rinvA * g0.y + b0.y;
        y.z = (pa0.z - muA) * rinvA * g0.z + b0.z;
        y.w = (pa0.w - muA) * rinvA * g0.w + b0.w;
        O4[i0] = y;
        y.x = (pa1.x - muA) * rinvA * g1.x + b1.x;
        y.y = (pa1.y - muA) * rinvA * g1.y + b1.y;
        y.z = (pa1.z - muA) * rinvA * g1.z + b1.z;
        y.w = (pa1.w - muA) * rinvA * g1.w + b1.w;
        O4[i0 + 64] = y;
        if (hasB) {
            y.x = (pb0.x - muB) * rinvB * g0.x + b0.x;
            y.y = (pb0.y - muB) * rinvB * g0.y + b0.y;
            y.z = (pb0.z - muB) * rinvB * g0.z + b0.z;
            y.w = (pb0.w - muB) * rinvB * g0.w + b0.w;
            O4[i0 + 128] = y;
            y.x = (pb1.x - muB) * rinvB * g1.x + b1.x;
            y.y = (pb1.y - muB) * rinvB * g1.y + b1.y;
            y.z = (pb1.z - muB) * rinvB * g1.z + b1.z;
            y.w = (pb1.w - muB) * rinvB * g1.w + b1.w;
            O4[i0 + 192] = y;
        }

        if (!more) break;
        base = nbase;
        i0   = (size_t)base * 128 + lane;
        xa0 = na0; xa1 = na1; xb0 = nb0; xb1 = nb1;
        hasB = nHasB;
    }
}

extern "C" void kernel_launch(void* const* d_in, const int* in_sizes, int n_in,
                              void* d_out, int out_size, void* d_ws, size_t ws_size,
                              hipStream_t stream)
{
    const float* Hm    = (const float*)d_in[0];
    const float* path  = (const float*)d_in[1];
    const float* Win1  = (const float*)d_in[2];
    const float* bin1  = (const float*)d_in[3];
    const float* Wout1 = (const float*)d_in[4];
    const float* bout1 = (const float*)d_in[5];
    const float* Win2  = (const float*)d_in[6];
    const float* bin2  = (const float*)d_in[7];
    const float* Wout2 = (const float*)d_in[8];
    const float* bout2 = (const float*)d_in[9];
    const float* ln1g  = (const float*)d_in[10];
    const float* ln1b  = (const float*)d_in[11];
    const float* ln2g  = (const float*)d_in[12];
    const float* ln2b  = (const float*)d_in[13];
    // d_in[14] = edge_index — unused by the reference
    const int*   ids   = (const int*)d_in[15];

    float* ws  = (float*)d_ws;
    float* out = (float*)d_out;
    const int N = in_sizes[0] / D;

    k_init<<<1, 128, 0, stream>>>((unsigned*)(ws + WS_FLAGS));
    k_chain<<<NCHAIN, 256, 0, stream>>>(Hm, path, Win1, bin1, Wout1, bout1,
                                        Win2, bin2, Wout2, bout2, ln1g, ln1b,
                                        ids, ws);
    k_final<<<2048, 256, 0, stream>>>(Hm, ws + WS_ATTN2, ln2g, ln2b, out, N);
}